// Round 17
// baseline (187.412 us; speedup 1.0000x reference)
//
#include <hip/hip_runtime.h>
#include <hip/hip_fp16.h>

#define SQ 1024

typedef __attribute__((ext_vector_type(8))) short short8;
typedef __attribute__((ext_vector_type(4))) float f32x4;
typedef __attribute__((ext_vector_type(4))) int i32x4;
typedef __attribute__((ext_vector_type(2))) unsigned int u32x2;

#define MFMA16(a,b,c) __builtin_amdgcn_mfma_f32_16x16x32_bf16((a),(b),(c),0,0,0)

static __device__ __forceinline__ float bf2f(unsigned short u){
  union { unsigned int i; float f; } v; v.i = ((unsigned int)u) << 16; return v.f;
}
static __device__ __forceinline__ unsigned short f2bf(float f){
  union { float fv; unsigned int i; } v; v.fv = f;
  unsigned int r = v.i + 0x7fffu + ((v.i >> 16) & 1u);
  return (unsigned short)(r >> 16);
}
static __device__ __forceinline__ void split_store(float val, unsigned short* hi, unsigned short* lo, int idx){
  unsigned short h = f2bf(val);
  hi[idx] = h;
  lo[idx] = f2bf(val - bf2f(h));
}

// async global->LDS, 16 bytes per lane (dest = uniform base + lane*16)
static __device__ __forceinline__ void gld_lds16(const float* g, float* d){
  __builtin_amdgcn_global_load_lds(
    static_cast<const unsigned int __attribute__((address_space(1)))*>(
        (const void __attribute__((address_space(1)))*)g),
    static_cast<unsigned int __attribute__((address_space(3)))*>(
        (void __attribute__((address_space(3)))*)d),
    16, 0, 0);
}

// pack two f32x4 (8 fp32) into hi/lo bf16 short8 fragments (truncation split)
static __device__ __forceinline__ void pack8(f32x4 u0, f32x4 u0b, short8& AHv, short8& ALv){
  unsigned int x0 = __float_as_uint(u0.x),  x1 = __float_as_uint(u0.y);
  unsigned int x2 = __float_as_uint(u0.z),  x3 = __float_as_uint(u0.w);
  unsigned int y0 = __float_as_uint(u0b.x), y1 = __float_as_uint(u0b.y);
  unsigned int y2 = __float_as_uint(u0b.z), y3 = __float_as_uint(u0b.w);
  float r0 = u0.x  - __uint_as_float(x0 & 0xffff0000u);
  float r1 = u0.y  - __uint_as_float(x1 & 0xffff0000u);
  float r2 = u0.z  - __uint_as_float(x2 & 0xffff0000u);
  float r3 = u0.w  - __uint_as_float(x3 & 0xffff0000u);
  float s0 = u0b.x - __uint_as_float(y0 & 0xffff0000u);
  float s1 = u0b.y - __uint_as_float(y1 & 0xffff0000u);
  float s2 = u0b.z - __uint_as_float(y2 & 0xffff0000u);
  float s3 = u0b.w - __uint_as_float(y3 & 0xffff0000u);
  union { unsigned int d[4]; short8 v; } AH, AL;
  AH.d[0] = (x0 >> 16) | (x1 & 0xffff0000u);
  AH.d[1] = (x2 >> 16) | (x3 & 0xffff0000u);
  AH.d[2] = (y0 >> 16) | (y1 & 0xffff0000u);
  AH.d[3] = (y2 >> 16) | (y3 & 0xffff0000u);
  AL.d[0] = (__float_as_uint(r0) >> 16) | (__float_as_uint(r1) & 0xffff0000u);
  AL.d[1] = (__float_as_uint(r2) >> 16) | (__float_as_uint(r3) & 0xffff0000u);
  AL.d[2] = (__float_as_uint(s0) >> 16) | (__float_as_uint(s1) & 0xffff0000u);
  AL.d[3] = (__float_as_uint(s2) >> 16) | (__float_as_uint(s3) & 0xffff0000u);
  AHv = AH.v; ALv = AL.v;
}

#define COMP4(v,e) ((e)==0?(v).x:(e)==1?(v).y:(e)==2?(v).z:(v).w)

#define QK_SCALE 0.17677669529663687f   // 1/sqrt(32), folded into q at gemm path
#define MASK_NEG -60000.0f              // fp16-safe mask (exp underflows to 0 in fp32)

// ---------------- fused prep: weight transpose+split | ww split | rmsnorm(s) ----------------
__global__ __launch_bounds__(256) void prep_all(
    const float* __restrict__ Wq, const float* __restrict__ Wk,
    const float* __restrict__ Wv, const float* __restrict__ Wg,
    const float* __restrict__ Wo,
    const float* __restrict__ wz, const float* __restrict__ Wz,
    const float* __restrict__ s, const float* __restrict__ w_s,
    unsigned short* __restrict__ wt_hi, unsigned short* __restrict__ wt_lo,
    unsigned short* __restrict__ wwh, unsigned short* __restrict__ wwl2,
    unsigned short* __restrict__ s_hi, unsigned short* __restrict__ s_lo){
  __shared__ __align__(16) float tile[32][33];
  int bid = blockIdx.x;
  int t = threadIdx.x;
  if (bid < 720){
    int bx = bid % 60, by = bid / 60;
    int tx = t & 31, ty = t >> 5;
    int nt = bx * 32, kt = by * 32;
    int nb = nt / 384;
    const float* W = (nb==0)?Wq:(nb==1)?Wk:(nb==2)?Wv:(nb==3)?Wg:Wo;
    int nn0 = nt - nb*384;
    #pragma unroll
    for (int yy=0; yy<4; yy++){
      int k = kt + ty + yy*8;
      tile[ty + yy*8][tx] = W[k*384 + nn0 + tx];
    }
    __syncthreads();
    #pragma unroll
    for (int yy=0; yy<4; yy++){
      int n = nt + ty + yy*8;
      int k = kt + tx;
      float v = tile[tx][ty + yy*8];
      split_store(v, wt_hi, wt_lo, n*384 + k);
    }
  } else if (bid == 720){
    for (int idx = t; idx < 2048; idx += 256){
      int c = idx >> 4, h = idx & 15;
      float val = (h < 12) ? wz[c]*Wz[c*12 + h] : 0.f;
      unsigned short hh = f2bf(val);
      wwh[idx] = hh;
      wwl2[idx] = f2bf(val - bf2f(hh));
    }
  } else {
    int wv = t >> 6, lane = t & 63;
    int row = (bid - 721)*4 + wv;
    const float* sr = s + row*384;
    float v[6]; float ss = 0.f;
    #pragma unroll
    for (int q=0;q<6;q++){ v[q] = sr[lane + q*64]; ss += v[q]*v[q]; }
    #pragma unroll
    for (int m=1;m<64;m<<=1) ss += __shfl_xor(ss, m);
    float rs = rsqrtf(ss*(1.f/384.f) + 1e-5f);
    #pragma unroll
    for (int q=0;q<6;q++){
      int c = lane + q*64;
      split_store(v[q]*rs*w_s[c], s_hi, s_lo, row*384 + c);
    }
  }
}

// ---------------- MERGED: gemm_qkvg (bid<384) + bias_k (bid>=384) ----------------
// bias v12: 3-slot half-tile ring (12KB/wave, union 48.3KB -> 3 blocks/CU, 12
// waves). Prefetch depth 2 (8KB in flight/wave, 96KB/CU). Counted waits:
// steady vmcnt(8) (8 newest = S(ht+1)+S(ht+2); S(ht)+older stores drained),
// tail 4/0. Staging/compute identical to v11 (copy-parity request rate).
__global__ __launch_bounds__(256,3) void qkvg_bias_k(
    const unsigned short* __restrict__ Ah, const unsigned short* __restrict__ Al,
    const unsigned short* __restrict__ Bh2, const unsigned short* __restrict__ Bl2,
    const float* __restrict__ bg,
    unsigned short* __restrict__ q_hi, unsigned short* __restrict__ q_lo,
    unsigned short* __restrict__ k_hi, unsigned short* __restrict__ k_lo,
    unsigned short* __restrict__ v_hi, unsigned short* __restrict__ v_lo,
    float* __restrict__ g,
    const float* __restrict__ z, const int* __restrict__ zm,
    const unsigned short* __restrict__ wwh, const unsigned short* __restrict__ wwl2,
    __half* __restrict__ biasH){
  __shared__ __align__(16) char smem[49408];   // union: gemm 20.5KB | bias 48KB+256B
  int bid = blockIdx.x;
  int t = threadIdx.x, w = t >> 6, lane = t & 63;
  int fr = lane & 15, fg = lane >> 4;

  if (bid < 384){
    // ================= gemm_qkvg path =================
    unsigned short* lah = (unsigned short*)smem;
    unsigned short* lal = (unsigned short*)(smem + 5120);
    unsigned short* lbh = (unsigned short*)(smem + 10240);
    unsigned short* lbl = (unsigned short*)(smem + 15360);
    int m0 = (bid / 24) * 64, n0 = (bid % 24) * 64;
    f32x4 z4 = {0.f,0.f,0.f,0.f};
    f32x4 acc[4] = {z4, z4, z4, z4};
    int sr = t >> 2, sc = (t & 3) << 3;
    for (int k0 = 0; k0 < 384; k0 += 32){
      *(short8*)&lah[sr*40 + sc] = *(const short8*)&Ah[(m0+sr)*384 + k0 + sc];
      *(short8*)&lal[sr*40 + sc] = *(const short8*)&Al[(m0+sr)*384 + k0 + sc];
      *(short8*)&lbh[sr*40 + sc] = *(const short8*)&Bh2[(n0+sr)*384 + k0 + sc];
      *(short8*)&lbl[sr*40 + sc] = *(const short8*)&Bl2[(n0+sr)*384 + k0 + sc];
      __syncthreads();
      short8 a_h = *(short8*)&lah[(w*16+fr)*40 + (fg<<3)];
      short8 a_l = *(short8*)&lal[(w*16+fr)*40 + (fg<<3)];
      #pragma unroll
      for (int cf=0; cf<4; cf++){
        short8 b_h = *(short8*)&lbh[(cf*16+fr)*40 + (fg<<3)];
        short8 b_l = *(short8*)&lbl[(cf*16+fr)*40 + (fg<<3)];
        acc[cf] = MFMA16(a_h, b_h, acc[cf]);
        acc[cf] = MFMA16(a_h, b_l, acc[cf]);
        acc[cf] = MFMA16(a_l, b_h, acc[cf]);
      }
      __syncthreads();
    }
    int sec = n0 / 384;
    int nb0 = n0 - sec*384;
    #pragma unroll
    for (int cf=0; cf<4; cf++){
      #pragma unroll
      for (int jj=0; jj<4; jj++){
        int row = m0 + w*16 + (fg<<2) + jj;
        int nn = nb0 + cf*16 + fr;
        float val = acc[cf][jj];
        int hh = nn >> 5, dd = nn & 31;
        if (sec == 0)      split_store(val*QK_SCALE, q_hi, q_lo, (hh<<15) + (row<<5) + dd);
        else if (sec == 1) split_store(val, k_hi, k_lo, (hh<<15) + (row<<5) + dd);
        else if (sec == 2) split_store(val, v_hi, v_lo, (hh<<15) + dd*SQ + row);
        else               g[row*384 + nn] = val + bg[nn];
      }
    }
    return;
  }

  // ================= bias path v12 =================
  int wid = ((bid - 384) << 2) + w;                 // global wave id 0..8191
  float* zbuf  = (float*)smem;                      // [4 waves][3 slots][1024 floats]
  float* rsbuf = (float*)(smem + 49152);            // [4 waves][16]
  int q4 = lane >> 4, l16 = lane & 15;

  // B fragments: WW[c = kt*32 + fg*8 + e][h = fr], hi/lo
  short8 Bh[4], Bl[4];
  #pragma unroll
  for (int kt=0; kt<4; kt++){
    #pragma unroll
    for (int e=0; e<8; e++){
      int c = kt*32 + (fg<<3) + e;
      Bh[kt][e] = (short)wwh[(c<<4) + fr];
      Bl[kt][e] = (short)wwl2[(c<<4) + fr];
    }
  }

  // zm upfront (8 tiles x i32x4; full unroll keeps indices static)
  i32x4 zmv[8];
  #pragma unroll
  for (int tt=0; tt<8; tt++){
    size_t tile = (size_t)tt*8192 + (size_t)wid;
    int ii = (int)(tile >> 6), jj0 = ((int)tile & 63) << 4;
    zmv[tt] = *(const i32x4*)&zm[ii*SQ + jj0 + (fg<<2)];
  }

  // STAGE half-tile HT (0..15): tile = HT>>1, col-half = HT&1, slot = HT%3.
  #define STAGE(HT)                                                          \
    {                                                                        \
      size_t tile = (size_t)((HT)>>1)*8192 + (size_t)wid;                    \
      const float* zs = z + tile*2048 + (((HT)&1)<<6);                       \
      float* db = zbuf + (w*3 + ((HT)%3))*1024;                              \
      _Pragma("unroll")                                                      \
      for (int n=0; n<4; ++n){                                               \
        int r = (n<<2) + q4;                                                 \
        gld_lds16(zs + r*128 + ((l16 ^ (r&7)) << 2), db + n*256);            \
      }                                                                      \
    }

  STAGE(0) STAGE(1)

  f32x4 acc0 = {0.f,0.f,0.f,0.f};
  float ssq0 = 0.f;
  int r7 = fr & 7;

  #pragma unroll
  for (int ht = 0; ht < 16; ++ht){
    if (ht + 2 < 16) STAGE(ht+2)
    if (ht < 14)       asm volatile("s_waitcnt vmcnt(8)"  ::: "memory");
    else if (ht == 14) asm volatile("s_waitcnt vmcnt(4)"  ::: "memory");
    else               asm volatile("s_waitcnt vmcnt(0)"  ::: "memory");

    if ((ht & 1) == 0){ acc0.x=0.f; acc0.y=0.f; acc0.z=0.f; acc0.w=0.f; ssq0 = 0.f; }

    const int zb = (w*3 + (ht%3))*1024;
    #pragma unroll
    for (int ktl=0; ktl<2; ++ktl){
      int kt = ((ht&1)<<1) + ktl;
      int g0 = (ktl<<3) + (fg<<1);
      f32x4 u0  = *(const f32x4*)&zbuf[zb + (fr<<6) + ((g0 ^ r7) << 2)];
      f32x4 u0b = *(const f32x4*)&zbuf[zb + (fr<<6) + (((g0+1) ^ r7) << 2)];
      ssq0 = fmaf(u0.x,u0.x,ssq0);   ssq0 = fmaf(u0.y,u0.y,ssq0);
      ssq0 = fmaf(u0.z,u0.z,ssq0);   ssq0 = fmaf(u0.w,u0.w,ssq0);
      ssq0 = fmaf(u0b.x,u0b.x,ssq0); ssq0 = fmaf(u0b.y,u0b.y,ssq0);
      ssq0 = fmaf(u0b.z,u0b.z,ssq0); ssq0 = fmaf(u0b.w,u0b.w,ssq0);
      short8 AHv, ALv;
      pack8(u0, u0b, AHv, ALv);
      acc0 = MFMA16(AHv, Bh[kt], acc0);
      acc0 = MFMA16(AHv, Bl[kt], acc0);
      acc0 = MFMA16(ALv, Bh[kt], acc0);
    }

    if (ht & 1){
      int tt = ht >> 1;
      float sq = ssq0;
      sq += __shfl_xor(sq, 16); sq += __shfl_xor(sq, 32);
      if (lane < 16)
        rsbuf[(w<<4) + lane] = rsqrtf(sq*(1.0f/128.0f) + 1e-5f);
      int jo = fg << 2;
      f32x4 rs0 = *(const f32x4*)&rsbuf[(w<<4) + jo];
      i32x4 Z = zmv[tt];
      f32x4 mk0;
      mk0.x = (Z.x != 0) ? 0.f : MASK_NEG;
      mk0.y = (Z.y != 0) ? 0.f : MASK_NEG;
      mk0.z = (Z.z != 0) ? 0.f : MASK_NEG;
      mk0.w = (Z.w != 0) ? 0.f : MASK_NEG;
      if (fr < 12){
        size_t tile = (size_t)tt*8192 + (size_t)wid;
        int ii = (int)(tile >> 6), jj0 = ((int)tile & 63) << 4;
        size_t hb = (size_t)ii*12288 + (size_t)fr*SQ + jj0;
        union { __half2 h2[2]; u32x2 u; } pk;
        pk.h2[0] = __floats2half2_rn(fmaf(acc0[0], rs0.x, mk0.x),
                                     fmaf(acc0[1], rs0.y, mk0.y));
        pk.h2[1] = __floats2half2_rn(fmaf(acc0[2], rs0.z, mk0.z),
                                     fmaf(acc0[3], rs0.w, mk0.w));
        __builtin_nontemporal_store(pk.u, (u32x2*)&biasH[hb + jo]);
      }
    }
  }
  #undef STAGE
}

// ---------------- attention v3: 384 blocks x 2 sequential units (no tail round) ----------------
__global__ __launch_bounds__(256) void attn_k(
    const unsigned short* __restrict__ qh_, const unsigned short* __restrict__ ql_,
    const unsigned short* __restrict__ kh_, const unsigned short* __restrict__ kl_,
    const unsigned short* __restrict__ vh_, const unsigned short* __restrict__ vl_,
    const __half* __restrict__ biasH,
    unsigned short* __restrict__ oh_, unsigned short* __restrict__ ol_){
  __shared__ __align__(16) float Sl[16*1028];     // 65.8KB, row stride 1028
  __shared__ __align__(16) float Opart[4*512];    // 8KB partial O per wave
  __shared__ float rsl[16];                        // 1/sum per row
  int t = threadIdx.x, wv = t >> 6, lane = t & 63;
  int fr = lane & 15, fg = lane >> 4;

  #pragma unroll 1
  for (int u = 0; u < 2; u++){
    int unit = (blockIdx.x << 1) | u;
    int h = unit >> 6;
    int i0 = (unit & 63) << 4;
    int hbase = h << 15;
    const unsigned short* qh = qh_ + hbase; const unsigned short* ql = ql_ + hbase;
    const unsigned short* kh = kh_ + hbase; const unsigned short* kl = kl_ + hbase;
    const unsigned short* vh = vh_ + hbase; const unsigned short* vl = vl_ + hbase;

    short8 aqh = *(const short8*)&qh[((i0 + fr) << 5) + (fg << 3)];
    short8 aql = *(const short8*)&ql[((i0 + fr) << 5) + (fg << 3)];

    // ---- QK^T: wave's 16 j-tiles ----
    #pragma unroll 4
    for (int jt = 0; jt < 16; jt++){
      int j0 = (wv << 8) + (jt << 4);
      short8 bkh = *(const short8*)&kh[((j0 + fr) << 5) + (fg << 3)];
      short8 bkl = *(const short8*)&kl[((j0 + fr) << 5) + (fg << 3)];
      f32x4 a = {0.f,0.f,0.f,0.f};
      a = MFMA16(aqh, bkh, a);
      a = MFMA16(aqh, bkl, a);
      a = MFMA16(aql, bkh, a);
      #pragma unroll
      for (int jj=0; jj<4; jj++)
        Sl[(fg*4 + jj)*1028 + j0 + fr] = a[jj];
    }
    __syncthreads();

    // ---- softmax: row = t>>4, 16 lanes/row, f32x4 passes, fused fp16 bias add ----
    {
      int row = t >> 4, l16 = t & 15;
      float* Srow = &Sl[row*1028];
      const __half* brow = biasH + (size_t)(i0 + row)*12288 + (size_t)h*SQ;
      float mx = -3.0e38f;
      #pragma unroll 4
      for (int cc=0; cc<16; cc++){
        int j = (l16 + cc*16) << 2;
        f32x4 sv = *(f32x4*)&Srow[j];
        union { u32x2 uu; __half2 h2[2]; } bv;
        bv.uu = *(const u32x2*)&brow[j];
        float2 f01 = __half22float2(bv.h2[0]);
        float2 f23 = __half22float2(bv.h2[1]);
        sv.x += f01.x; sv.y += f01.y; sv.z += f23.x; sv.w += f23.y;
        *(f32x4*)&Srow[j] = sv;
        mx = fmaxf(mx, fmaxf(fmaxf(sv.x, sv.y), fmaxf(sv.z, sv.w)));
      }
      mx = fmaxf(mx, __shfl_xor(mx, 1));
      mx = fmaxf(mx, __shfl_xor(mx, 2));
      mx = fmaxf(mx, __shfl_xor(mx, 4));
      mx = fmaxf(mx, __shfl_xor(mx, 8));
      float sm = 0.f;
      #pragma unroll 4
      for (int cc=0; cc<16; cc++){
        int j = (l16 + cc*16) << 2;
        f32x4 sv = *(f32x4*)&Srow[j];
        sv.x = __expf(sv.x - mx); sv.y = __expf(sv.y - mx);
        sv.z = __expf(sv.z - mx); sv.w = __expf(sv.w - mx);
        *(f32x4*)&Srow[j] = sv;
        sm += sv.x + sv.y + sv.z + sv.w;
      }
      sm += __shfl_xor(sm, 1);
      sm += __shfl_xor(sm, 2);
      sm += __shfl_xor(sm, 4);
      sm += __shfl_xor(sm, 8);
      if (l16 == 0) rsl[row] = 1.0f / sm;
    }
    __syncthreads();

    // ---- PV: wave k-slice, all lanes, 16 q-rows ----
    f32x4 o0 = {0.f,0.f,0.f,0.f}, o1 = {0.f,0.f,0.f,0.f};
    #pragma unroll 2
    for (int kk=0; kk<8; kk++){
      int k0 = (wv << 8) + (kk << 5);
      f32x4 pa = *(const f32x4*)&Sl[fr*1028 + k0 + (fg<<3)];
      f32x4 pb = *(const f32x4*)&Sl[fr*1028 + k0 + (fg<<3) + 4];
      short8 ph, pl;
      pack8(pa, pb, ph, pl);
      short8 v0h = *(const short8*)&vh[fr*SQ + k0 + (fg<<3)];
      short8 v0l = *(const short8*)&vl[fr*SQ + k0 + (fg<<3)];
      short8 v1h = *(const short8*)&vh[(16+fr)*SQ + k0 + (fg<<3)];
      short8 v1l = *(const short8*)&vl[(16+fr)*SQ + k0 + (fg<<3)];
      o0 = MFMA16(ph, v0h, o0); o0 = MFMA16(ph, v0l, o0); o0 = MFMA16(pl, v0h, o0);
      o1 = MFMA16(ph, v1h, o1); o1 = MFMA16(ph, v1l, o1); o1 = MFMA16(pl, v1h, o1);
    }
    {
      float* op = &Opart[wv*512];
      #pragma unroll
      for (int jj=0; jj<4; jj++){
        op[(fg*4 + jj)*32 + fr]      = o0[jj];
        op[(fg*4 + jj)*32 + 16 + fr] = o1[jj];
      }
    }
    __syncthreads();

    // ---- cross-wave reduce + normalized store ----
    #pragma unroll
    for (int uu=0; uu<2; uu++){
      int idx = t + uu*256;
      int q = idx >> 5, d = idx & 31;
      float v = Opart[q*32 + d] + Opart[512 + q*32 + d]
              + Opart[1024 + q*32 + d] + Opart[1536 + q*32 + d];
      v *= rsl[q];
      split_store(v, oh_, ol_, (i0 + q)*384 + (h << 5) + d);
    }
    __syncthreads();   // Opart/rsl safe before next unit overwrites
  }
}

// ---------------- GEMM2 v2: 32x64 tiles (192 blocks), (o @ Wo + bo) * g ----------------
__global__ __launch_bounds__(256) void gemm_out_k(
    const unsigned short* __restrict__ Ah, const unsigned short* __restrict__ Al,
    const unsigned short* __restrict__ Bh, const unsigned short* __restrict__ Bl,
    const float* __restrict__ bo, const float* __restrict__ g,
    float* __restrict__ out){
  __shared__ __align__(16) unsigned short lah[32*40], lal[32*40], lbh[64*40], lbl[64*40];
  int t = threadIdx.x, wv = t >> 6, lane = t & 63;
  int m0 = blockIdx.y * 32, n0 = blockIdx.x * 64;
  int fr = lane & 15, fg = lane >> 4;
  int ms = (wv & 1) << 4, ns = (wv >> 1) << 5;
  f32x4 z4 = {0.f,0.f,0.f,0.f};
  f32x4 acc[2] = {z4, z4};
  int sr = t >> 2, sc = (t & 3) << 3;
  for (int k0 = 0; k0 < 384; k0 += 32){
    if (t < 128){
      *(short8*)&lah[sr*40 + sc] = *(const short8*)&Ah[(m0+sr)*384 + k0 + sc];
      *(short8*)&lal[sr*40 + sc] = *(const short8*)&Al[(m0+sr)*384 + k0 + sc];
    }
    *(short8*)&lbh[sr*40 + sc] = *(const short8*)&Bh[(n0+sr)*384 + k0 + sc];
    *(short8*)&lbl[sr*40 + sc] = *(const short8*)&Bl[(n0+sr)*384 + k0 + sc];
    __syncthreads();
    short8 a_h = *(short8*)&lah[(ms+fr)*40 + (fg<<3)];
    short8 a_l = *(short8*)&lal[(ms+fr)*40 + (fg<<3)];
    #pragma unroll
    for (int cf=0; cf<2; cf++){
      short8 b_h = *(short8*)&lbh[(ns + cf*16 + fr)*40 + (fg<<3)];
      short8 b_l = *(short8*)&lbl[(ns + cf*16 + fr)*40 + (fg<<3)];
      acc[cf] = MFMA16(a_h, b_h, acc[cf]);
      acc[cf] = MFMA16(a_h, b_l, acc[cf]);
      acc[cf] = MFMA16(a_l, b_h, acc[cf]);
    }
    __syncthreads();
  }
  #pragma unroll
  for (int cf=0; cf<2; cf++){
    #pragma unroll
    for (int jj=0; jj<4; jj++){
      int row = m0 + ms + (fg<<2) + jj;
      int col = n0 + ns + cf*16 + fr;
      out[row*384 + col] = (acc[cf][jj] + bo[col]) * g[row*384 + col];
    }
  }
}

// ---------------- launch ----------------
extern "C" void kernel_launch(void* const* d_in, const int* in_sizes, int n_in,
                              void* d_out, int out_size, void* d_ws, size_t ws_size,
                              hipStream_t stream) {
  const float* s   = (const float*)d_in[0];
  const float* z   = (const float*)d_in[1];
  const int*   zm  = (const int*)d_in[2];
  const float* w_s = (const float*)d_in[3];
  const float* w_z = (const float*)d_in[4];
  const float* Wz  = (const float*)d_in[5];
  const float* Wq  = (const float*)d_in[6];
  const float* Wk  = (const float*)d_in[7];
  const float* Wv  = (const float*)d_in[8];
  const float* Wg  = (const float*)d_in[9];
  const float* bg  = (const float*)d_in[10];
  const float* Wo  = (const float*)d_in[11];
  const float* bo  = (const float*)d_in[12];
  float* out = (float*)d_out;
  char* ws = (char*)d_ws;

  unsigned short* s_hi  = (unsigned short*)(ws + 0);
  unsigned short* s_lo  = (unsigned short*)(ws + 786432);
  unsigned short* wt_hi = (unsigned short*)(ws + 1572864);   // [1920][384]
  unsigned short* wt_lo = (unsigned short*)(ws + 3047424);
  unsigned short* wwh   = (unsigned short*)(ws + 4521984);   // [128][16] bf16 hi
  unsigned short* wwl2  = (unsigned short*)(ws + 4526080);   // [128][16] bf16 lo
  unsigned short* q_hi  = (unsigned short*)(ws + 4532224);   // [12][1024][32]
  unsigned short* q_lo  = (unsigned short*)(ws + 5318656);
  unsigned short* k_hi  = (unsigned short*)(ws + 6105088);
  unsigned short* k_lo  = (unsigned short*)(ws + 6891520);
  unsigned short* v_hi  = (unsigned short*)(ws + 7677952);   // [12][32][1024] (transposed)
  unsigned short* v_lo  = (unsigned short*)(ws + 8464384);
  float*          gbuf  = (float*)(ws + 9250816);            // [1024][384] fp32
  unsigned short* o_hi  = (unsigned short*)(ws + 10823680);  // [1024][384]
  unsigned short* o_lo  = (unsigned short*)(ws + 11610112);
  __half*         biasH = (__half*)(ws + 12396544);          // [1024][12][1024] fp16, 24MB

  prep_all<<<977, 256, 0, stream>>>(Wq, Wk, Wv, Wg, Wo, w_z, Wz, s, w_s,
                                    wt_hi, wt_lo, wwh, wwl2, s_hi, s_lo);
  qkvg_bias_k<<<2432, 256, 0, stream>>>(s_hi, s_lo, wt_hi, wt_lo, bg,
                                        q_hi, q_lo, k_hi, k_lo, v_hi, v_lo, gbuf,
                                        z, zm, wwh, wwl2, biasH);
  attn_k<<<384, 256, 0, stream>>>(q_hi, q_lo, k_hi, k_lo, v_hi, v_lo, biasH, o_hi, o_lo);
  gemm_out_k<<<dim3(6,32), 256, 0, stream>>>(o_hi, o_lo,
                                             wt_hi + 1536*384, wt_lo + 1536*384,
                                             bo, gbuf, out);
}

// Round 18
// 178.245 us; speedup vs baseline: 1.0514x; 1.0514x over previous
//
#include <hip/hip_runtime.h>
#include <hip/hip_fp16.h>

#define SQ 1024

typedef __attribute__((ext_vector_type(8))) short short8;
typedef __attribute__((ext_vector_type(4))) float f32x4;
typedef __attribute__((ext_vector_type(4))) int i32x4;
typedef __attribute__((ext_vector_type(2))) unsigned int u32x2;

#define MFMA16(a,b,c) __builtin_amdgcn_mfma_f32_16x16x32_bf16((a),(b),(c),0,0,0)

static __device__ __forceinline__ float bf2f(unsigned short u){
  union { unsigned int i; float f; } v; v.i = ((unsigned int)u) << 16; return v.f;
}
static __device__ __forceinline__ unsigned short f2bf(float f){
  union { float fv; unsigned int i; } v; v.fv = f;
  unsigned int r = v.i + 0x7fffu + ((v.i >> 16) & 1u);
  return (unsigned short)(r >> 16);
}
static __device__ __forceinline__ void split_store(float val, unsigned short* hi, unsigned short* lo, int idx){
  unsigned short h = f2bf(val);
  hi[idx] = h;
  lo[idx] = f2bf(val - bf2f(h));
}

// async global->LDS, 16 bytes per lane (dest = uniform base + lane*16)
static __device__ __forceinline__ void gld_lds16(const float* g, float* d){
  __builtin_amdgcn_global_load_lds(
    static_cast<const unsigned int __attribute__((address_space(1)))*>(
        (const void __attribute__((address_space(1)))*)g),
    static_cast<unsigned int __attribute__((address_space(3)))*>(
        (void __attribute__((address_space(3)))*)d),
    16, 0, 0);
}

// pack two f32x4 (8 fp32) into hi/lo bf16 short8 fragments (truncation split)
static __device__ __forceinline__ void pack8(f32x4 u0, f32x4 u0b, short8& AHv, short8& ALv){
  unsigned int x0 = __float_as_uint(u0.x),  x1 = __float_as_uint(u0.y);
  unsigned int x2 = __float_as_uint(u0.z),  x3 = __float_as_uint(u0.w);
  unsigned int y0 = __float_as_uint(u0b.x), y1 = __float_as_uint(u0b.y);
  unsigned int y2 = __float_as_uint(u0b.z), y3 = __float_as_uint(u0b.w);
  float r0 = u0.x  - __uint_as_float(x0 & 0xffff0000u);
  float r1 = u0.y  - __uint_as_float(x1 & 0xffff0000u);
  float r2 = u0.z  - __uint_as_float(x2 & 0xffff0000u);
  float r3 = u0.w  - __uint_as_float(x3 & 0xffff0000u);
  float s0 = u0b.x - __uint_as_float(y0 & 0xffff0000u);
  float s1 = u0b.y - __uint_as_float(y1 & 0xffff0000u);
  float s2 = u0b.z - __uint_as_float(y2 & 0xffff0000u);
  float s3 = u0b.w - __uint_as_float(y3 & 0xffff0000u);
  union { unsigned int d[4]; short8 v; } AH, AL;
  AH.d[0] = (x0 >> 16) | (x1 & 0xffff0000u);
  AH.d[1] = (x2 >> 16) | (x3 & 0xffff0000u);
  AH.d[2] = (y0 >> 16) | (y1 & 0xffff0000u);
  AH.d[3] = (y2 >> 16) | (y3 & 0xffff0000u);
  AL.d[0] = (__float_as_uint(r0) >> 16) | (__float_as_uint(r1) & 0xffff0000u);
  AL.d[1] = (__float_as_uint(r2) >> 16) | (__float_as_uint(r3) & 0xffff0000u);
  AL.d[2] = (__float_as_uint(s0) >> 16) | (__float_as_uint(s1) & 0xffff0000u);
  AL.d[3] = (__float_as_uint(s2) >> 16) | (__float_as_uint(s3) & 0xffff0000u);
  AHv = AH.v; ALv = AL.v;
}

#define COMP4(v,e) ((e)==0?(v).x:(e)==1?(v).y:(e)==2?(v).z:(v).w)

#define QK_SCALE 0.17677669529663687f   // 1/sqrt(32), folded into q at gemm path
#define MASK_NEG -60000.0f              // fp16-safe mask (exp underflows to 0 in fp32)

// ---------------- fused prep: weight transpose+split | ww split | rmsnorm(s) ----------------
__global__ __launch_bounds__(256) void prep_all(
    const float* __restrict__ Wq, const float* __restrict__ Wk,
    const float* __restrict__ Wv, const float* __restrict__ Wg,
    const float* __restrict__ Wo,
    const float* __restrict__ wz, const float* __restrict__ Wz,
    const float* __restrict__ s, const float* __restrict__ w_s,
    unsigned short* __restrict__ wt_hi, unsigned short* __restrict__ wt_lo,
    unsigned short* __restrict__ wwh, unsigned short* __restrict__ wwl2,
    unsigned short* __restrict__ s_hi, unsigned short* __restrict__ s_lo){
  __shared__ __align__(16) float tile[32][33];
  int bid = blockIdx.x;
  int t = threadIdx.x;
  if (bid < 720){
    int bx = bid % 60, by = bid / 60;
    int tx = t & 31, ty = t >> 5;
    int nt = bx * 32, kt = by * 32;
    int nb = nt / 384;
    const float* W = (nb==0)?Wq:(nb==1)?Wk:(nb==2)?Wv:(nb==3)?Wg:Wo;
    int nn0 = nt - nb*384;
    #pragma unroll
    for (int yy=0; yy<4; yy++){
      int k = kt + ty + yy*8;
      tile[ty + yy*8][tx] = W[k*384 + nn0 + tx];
    }
    __syncthreads();
    #pragma unroll
    for (int yy=0; yy<4; yy++){
      int n = nt + ty + yy*8;
      int k = kt + tx;
      float v = tile[tx][ty + yy*8];
      split_store(v, wt_hi, wt_lo, n*384 + k);
    }
  } else if (bid == 720){
    for (int idx = t; idx < 2048; idx += 256){
      int c = idx >> 4, h = idx & 15;
      float val = (h < 12) ? wz[c]*Wz[c*12 + h] : 0.f;
      unsigned short hh = f2bf(val);
      wwh[idx] = hh;
      wwl2[idx] = f2bf(val - bf2f(hh));
    }
  } else {
    int wv = t >> 6, lane = t & 63;
    int row = (bid - 721)*4 + wv;
    const float* sr = s + row*384;
    float v[6]; float ss = 0.f;
    #pragma unroll
    for (int q=0;q<6;q++){ v[q] = sr[lane + q*64]; ss += v[q]*v[q]; }
    #pragma unroll
    for (int m=1;m<64;m<<=1) ss += __shfl_xor(ss, m);
    float rs = rsqrtf(ss*(1.f/384.f) + 1e-5f);
    #pragma unroll
    for (int q=0;q<6;q++){
      int c = lane + q*64;
      split_store(v[q]*rs*w_s[c], s_hi, s_lo, row*384 + c);
    }
  }
}

// ---------------- MERGED: gemm_qkvg (bid<384) + bias_k (bid>=384) ----------------
// bias v13 = v12 with PLAIN bias stores (NT removed store-side only): per tile a
// row receives 32B halves from adjacent waves; NT evicted them before merge ->
// partial-line DRAM writes (~2x write amplification). Plain stores let L2
// write-combine. z loads stay NT (512MB stream, no reuse).
__global__ __launch_bounds__(256,3) void qkvg_bias_k(
    const unsigned short* __restrict__ Ah, const unsigned short* __restrict__ Al,
    const unsigned short* __restrict__ Bh2, const unsigned short* __restrict__ Bl2,
    const float* __restrict__ bg,
    unsigned short* __restrict__ q_hi, unsigned short* __restrict__ q_lo,
    unsigned short* __restrict__ k_hi, unsigned short* __restrict__ k_lo,
    unsigned short* __restrict__ v_hi, unsigned short* __restrict__ v_lo,
    float* __restrict__ g,
    const float* __restrict__ z, const int* __restrict__ zm,
    const unsigned short* __restrict__ wwh, const unsigned short* __restrict__ wwl2,
    __half* __restrict__ biasH){
  __shared__ __align__(16) char smem[49408];   // union: gemm 20.5KB | bias 48KB+256B
  int bid = blockIdx.x;
  int t = threadIdx.x, w = t >> 6, lane = t & 63;
  int fr = lane & 15, fg = lane >> 4;

  if (bid < 384){
    // ================= gemm_qkvg path =================
    unsigned short* lah = (unsigned short*)smem;
    unsigned short* lal = (unsigned short*)(smem + 5120);
    unsigned short* lbh = (unsigned short*)(smem + 10240);
    unsigned short* lbl = (unsigned short*)(smem + 15360);
    int m0 = (bid / 24) * 64, n0 = (bid % 24) * 64;
    f32x4 z4 = {0.f,0.f,0.f,0.f};
    f32x4 acc[4] = {z4, z4, z4, z4};
    int sr = t >> 2, sc = (t & 3) << 3;
    for (int k0 = 0; k0 < 384; k0 += 32){
      *(short8*)&lah[sr*40 + sc] = *(const short8*)&Ah[(m0+sr)*384 + k0 + sc];
      *(short8*)&lal[sr*40 + sc] = *(const short8*)&Al[(m0+sr)*384 + k0 + sc];
      *(short8*)&lbh[sr*40 + sc] = *(const short8*)&Bh2[(n0+sr)*384 + k0 + sc];
      *(short8*)&lbl[sr*40 + sc] = *(const short8*)&Bl2[(n0+sr)*384 + k0 + sc];
      __syncthreads();
      short8 a_h = *(short8*)&lah[(w*16+fr)*40 + (fg<<3)];
      short8 a_l = *(short8*)&lal[(w*16+fr)*40 + (fg<<3)];
      #pragma unroll
      for (int cf=0; cf<4; cf++){
        short8 b_h = *(short8*)&lbh[(cf*16+fr)*40 + (fg<<3)];
        short8 b_l = *(short8*)&lbl[(cf*16+fr)*40 + (fg<<3)];
        acc[cf] = MFMA16(a_h, b_h, acc[cf]);
        acc[cf] = MFMA16(a_h, b_l, acc[cf]);
        acc[cf] = MFMA16(a_l, b_h, acc[cf]);
      }
      __syncthreads();
    }
    int sec = n0 / 384;
    int nb0 = n0 - sec*384;
    #pragma unroll
    for (int cf=0; cf<4; cf++){
      #pragma unroll
      for (int jj=0; jj<4; jj++){
        int row = m0 + w*16 + (fg<<2) + jj;
        int nn = nb0 + cf*16 + fr;
        float val = acc[cf][jj];
        int hh = nn >> 5, dd = nn & 31;
        if (sec == 0)      split_store(val*QK_SCALE, q_hi, q_lo, (hh<<15) + (row<<5) + dd);
        else if (sec == 1) split_store(val, k_hi, k_lo, (hh<<15) + (row<<5) + dd);
        else if (sec == 2) split_store(val, v_hi, v_lo, (hh<<15) + dd*SQ + row);
        else               g[row*384 + nn] = val + bg[nn];
      }
    }
    return;
  }

  // ================= bias path v13 =================
  int wid = ((bid - 384) << 2) + w;                 // global wave id 0..8191
  float* zbuf  = (float*)smem;                      // [4 waves][3 slots][1024 floats]
  float* rsbuf = (float*)(smem + 49152);            // [4 waves][16]
  int q4 = lane >> 4, l16 = lane & 15;

  // B fragments: WW[c = kt*32 + fg*8 + e][h = fr], hi/lo
  short8 Bh[4], Bl[4];
  #pragma unroll
  for (int kt=0; kt<4; kt++){
    #pragma unroll
    for (int e=0; e<8; e++){
      int c = kt*32 + (fg<<3) + e;
      Bh[kt][e] = (short)wwh[(c<<4) + fr];
      Bl[kt][e] = (short)wwl2[(c<<4) + fr];
    }
  }

  // zm upfront (8 tiles x i32x4; full unroll keeps indices static)
  i32x4 zmv[8];
  #pragma unroll
  for (int tt=0; tt<8; tt++){
    size_t tile = (size_t)tt*8192 + (size_t)wid;
    int ii = (int)(tile >> 6), jj0 = ((int)tile & 63) << 4;
    zmv[tt] = *(const i32x4*)&zm[ii*SQ + jj0 + (fg<<2)];
  }

  // STAGE half-tile HT (0..15): tile = HT>>1, col-half = HT&1, slot = HT%3.
  #define STAGE(HT)                                                          \
    {                                                                        \
      size_t tile = (size_t)((HT)>>1)*8192 + (size_t)wid;                    \
      const float* zs = z + tile*2048 + (((HT)&1)<<6);                       \
      float* db = zbuf + (w*3 + ((HT)%3))*1024;                              \
      _Pragma("unroll")                                                      \
      for (int n=0; n<4; ++n){                                               \
        int r = (n<<2) + q4;                                                 \
        gld_lds16(zs + r*128 + ((l16 ^ (r&7)) << 2), db + n*256);            \
      }                                                                      \
    }

  STAGE(0) STAGE(1)

  f32x4 acc0 = {0.f,0.f,0.f,0.f};
  float ssq0 = 0.f;
  int r7 = fr & 7;

  #pragma unroll
  for (int ht = 0; ht < 16; ++ht){
    if (ht + 2 < 16) STAGE(ht+2)
    if (ht < 14)       asm volatile("s_waitcnt vmcnt(8)"  ::: "memory");
    else if (ht == 14) asm volatile("s_waitcnt vmcnt(4)"  ::: "memory");
    else               asm volatile("s_waitcnt vmcnt(0)"  ::: "memory");

    if ((ht & 1) == 0){ acc0.x=0.f; acc0.y=0.f; acc0.z=0.f; acc0.w=0.f; ssq0 = 0.f; }

    const int zb = (w*3 + (ht%3))*1024;
    #pragma unroll
    for (int ktl=0; ktl<2; ++ktl){
      int kt = ((ht&1)<<1) + ktl;
      int g0 = (ktl<<3) + (fg<<1);
      f32x4 u0  = *(const f32x4*)&zbuf[zb + (fr<<6) + ((g0 ^ r7) << 2)];
      f32x4 u0b = *(const f32x4*)&zbuf[zb + (fr<<6) + (((g0+1) ^ r7) << 2)];
      ssq0 = fmaf(u0.x,u0.x,ssq0);   ssq0 = fmaf(u0.y,u0.y,ssq0);
      ssq0 = fmaf(u0.z,u0.z,ssq0);   ssq0 = fmaf(u0.w,u0.w,ssq0);
      ssq0 = fmaf(u0b.x,u0b.x,ssq0); ssq0 = fmaf(u0b.y,u0b.y,ssq0);
      ssq0 = fmaf(u0b.z,u0b.z,ssq0); ssq0 = fmaf(u0b.w,u0b.w,ssq0);
      short8 AHv, ALv;
      pack8(u0, u0b, AHv, ALv);
      acc0 = MFMA16(AHv, Bh[kt], acc0);
      acc0 = MFMA16(AHv, Bl[kt], acc0);
      acc0 = MFMA16(ALv, Bh[kt], acc0);
    }

    if (ht & 1){
      int tt = ht >> 1;
      float sq = ssq0;
      sq += __shfl_xor(sq, 16); sq += __shfl_xor(sq, 32);
      if (lane < 16)
        rsbuf[(w<<4) + lane] = rsqrtf(sq*(1.0f/128.0f) + 1e-5f);
      int jo = fg << 2;
      f32x4 rs0 = *(const f32x4*)&rsbuf[(w<<4) + jo];
      i32x4 Z = zmv[tt];
      f32x4 mk0;
      mk0.x = (Z.x != 0) ? 0.f : MASK_NEG;
      mk0.y = (Z.y != 0) ? 0.f : MASK_NEG;
      mk0.z = (Z.z != 0) ? 0.f : MASK_NEG;
      mk0.w = (Z.w != 0) ? 0.f : MASK_NEG;
      if (fr < 12){
        size_t tile = (size_t)tt*8192 + (size_t)wid;
        int ii = (int)(tile >> 6), jj0 = ((int)tile & 63) << 4;
        size_t hb = (size_t)ii*12288 + (size_t)fr*SQ + jj0;
        union { __half2 h2[2]; u32x2 u; } pk;
        pk.h2[0] = __floats2half2_rn(fmaf(acc0[0], rs0.x, mk0.x),
                                     fmaf(acc0[1], rs0.y, mk0.y));
        pk.h2[1] = __floats2half2_rn(fmaf(acc0[2], rs0.z, mk0.z),
                                     fmaf(acc0[3], rs0.w, mk0.w));
        *(u32x2*)&biasH[hb + jo] = pk.u;   // plain store: let L2 merge 32B halves
      }
    }
  }
  #undef STAGE
}

// ---------------- attention v3: 384 blocks x 2 sequential units (no tail round) ----------------
__global__ __launch_bounds__(256) void attn_k(
    const unsigned short* __restrict__ qh_, const unsigned short* __restrict__ ql_,
    const unsigned short* __restrict__ kh_, const unsigned short* __restrict__ kl_,
    const unsigned short* __restrict__ vh_, const unsigned short* __restrict__ vl_,
    const __half* __restrict__ biasH,
    unsigned short* __restrict__ oh_, unsigned short* __restrict__ ol_){
  __shared__ __align__(16) float Sl[16*1028];     // 65.8KB, row stride 1028
  __shared__ __align__(16) float Opart[4*512];    // 8KB partial O per wave
  __shared__ float rsl[16];                        // 1/sum per row
  int t = threadIdx.x, wv = t >> 6, lane = t & 63;
  int fr = lane & 15, fg = lane >> 4;

  #pragma unroll 1
  for (int u = 0; u < 2; u++){
    int unit = (blockIdx.x << 1) | u;
    int h = unit >> 6;
    int i0 = (unit & 63) << 4;
    int hbase = h << 15;
    const unsigned short* qh = qh_ + hbase; const unsigned short* ql = ql_ + hbase;
    const unsigned short* kh = kh_ + hbase; const unsigned short* kl = kl_ + hbase;
    const unsigned short* vh = vh_ + hbase; const unsigned short* vl = vl_ + hbase;

    short8 aqh = *(const short8*)&qh[((i0 + fr) << 5) + (fg << 3)];
    short8 aql = *(const short8*)&ql[((i0 + fr) << 5) + (fg << 3)];

    // ---- QK^T: wave's 16 j-tiles ----
    #pragma unroll 4
    for (int jt = 0; jt < 16; jt++){
      int j0 = (wv << 8) + (jt << 4);
      short8 bkh = *(const short8*)&kh[((j0 + fr) << 5) + (fg << 3)];
      short8 bkl = *(const short8*)&kl[((j0 + fr) << 5) + (fg << 3)];
      f32x4 a = {0.f,0.f,0.f,0.f};
      a = MFMA16(aqh, bkh, a);
      a = MFMA16(aqh, bkl, a);
      a = MFMA16(aql, bkh, a);
      #pragma unroll
      for (int jj=0; jj<4; jj++)
        Sl[(fg*4 + jj)*1028 + j0 + fr] = a[jj];
    }
    __syncthreads();

    // ---- softmax: row = t>>4, 16 lanes/row, f32x4 passes, fused fp16 bias add ----
    {
      int row = t >> 4, l16 = t & 15;
      float* Srow = &Sl[row*1028];
      const __half* brow = biasH + (size_t)(i0 + row)*12288 + (size_t)h*SQ;
      float mx = -3.0e38f;
      #pragma unroll 4
      for (int cc=0; cc<16; cc++){
        int j = (l16 + cc*16) << 2;
        f32x4 sv = *(f32x4*)&Srow[j];
        union { u32x2 uu; __half2 h2[2]; } bv;
        bv.uu = *(const u32x2*)&brow[j];
        float2 f01 = __half22float2(bv.h2[0]);
        float2 f23 = __half22float2(bv.h2[1]);
        sv.x += f01.x; sv.y += f01.y; sv.z += f23.x; sv.w += f23.y;
        *(f32x4*)&Srow[j] = sv;
        mx = fmaxf(mx, fmaxf(fmaxf(sv.x, sv.y), fmaxf(sv.z, sv.w)));
      }
      mx = fmaxf(mx, __shfl_xor(mx, 1));
      mx = fmaxf(mx, __shfl_xor(mx, 2));
      mx = fmaxf(mx, __shfl_xor(mx, 4));
      mx = fmaxf(mx, __shfl_xor(mx, 8));
      float sm = 0.f;
      #pragma unroll 4
      for (int cc=0; cc<16; cc++){
        int j = (l16 + cc*16) << 2;
        f32x4 sv = *(f32x4*)&Srow[j];
        sv.x = __expf(sv.x - mx); sv.y = __expf(sv.y - mx);
        sv.z = __expf(sv.z - mx); sv.w = __expf(sv.w - mx);
        *(f32x4*)&Srow[j] = sv;
        sm += sv.x + sv.y + sv.z + sv.w;
      }
      sm += __shfl_xor(sm, 1);
      sm += __shfl_xor(sm, 2);
      sm += __shfl_xor(sm, 4);
      sm += __shfl_xor(sm, 8);
      if (l16 == 0) rsl[row] = 1.0f / sm;
    }
    __syncthreads();

    // ---- PV: wave k-slice, all lanes, 16 q-rows ----
    f32x4 o0 = {0.f,0.f,0.f,0.f}, o1 = {0.f,0.f,0.f,0.f};
    #pragma unroll 2
    for (int kk=0; kk<8; kk++){
      int k0 = (wv << 8) + (kk << 5);
      f32x4 pa = *(const f32x4*)&Sl[fr*1028 + k0 + (fg<<3)];
      f32x4 pb = *(const f32x4*)&Sl[fr*1028 + k0 + (fg<<3) + 4];
      short8 ph, pl;
      pack8(pa, pb, ph, pl);
      short8 v0h = *(const short8*)&vh[fr*SQ + k0 + (fg<<3)];
      short8 v0l = *(const short8*)&vl[fr*SQ + k0 + (fg<<3)];
      short8 v1h = *(const short8*)&vh[(16+fr)*SQ + k0 + (fg<<3)];
      short8 v1l = *(const short8*)&vl[(16+fr)*SQ + k0 + (fg<<3)];
      o0 = MFMA16(ph, v0h, o0); o0 = MFMA16(ph, v0l, o0); o0 = MFMA16(pl, v0h, o0);
      o1 = MFMA16(ph, v1h, o1); o1 = MFMA16(ph, v1l, o1); o1 = MFMA16(pl, v1h, o1);
    }
    {
      float* op = &Opart[wv*512];
      #pragma unroll
      for (int jj=0; jj<4; jj++){
        op[(fg*4 + jj)*32 + fr]      = o0[jj];
        op[(fg*4 + jj)*32 + 16 + fr] = o1[jj];
      }
    }
    __syncthreads();

    // ---- cross-wave reduce + normalized store ----
    #pragma unroll
    for (int uu=0; uu<2; uu++){
      int idx = t + uu*256;
      int q = idx >> 5, d = idx & 31;
      float v = Opart[q*32 + d] + Opart[512 + q*32 + d]
              + Opart[1024 + q*32 + d] + Opart[1536 + q*32 + d];
      v *= rsl[q];
      split_store(v, oh_, ol_, (i0 + q)*384 + (h << 5) + d);
    }
    __syncthreads();   // Opart/rsl safe before next unit overwrites
  }
}

// ---------------- GEMM2 v2: 32x64 tiles (192 blocks), (o @ Wo + bo) * g ----------------
__global__ __launch_bounds__(256) void gemm_out_k(
    const unsigned short* __restrict__ Ah, const unsigned short* __restrict__ Al,
    const unsigned short* __restrict__ Bh, const unsigned short* __restrict__ Bl,
    const float* __restrict__ bo, const float* __restrict__ g,
    float* __restrict__ out){
  __shared__ __align__(16) unsigned short lah[32*40], lal[32*40], lbh[64*40], lbl[64*40];
  int t = threadIdx.x, wv = t >> 6, lane = t & 63;
  int m0 = blockIdx.y * 32, n0 = blockIdx.x * 64;
  int fr = lane & 15, fg = lane >> 4;
  int ms = (wv & 1) << 4, ns = (wv >> 1) << 5;
  f32x4 z4 = {0.f,0.f,0.f,0.f};
  f32x4 acc[2] = {z4, z4};
  int sr = t >> 2, sc = (t & 3) << 3;
  for (int k0 = 0; k0 < 384; k0 += 32){
    if (t < 128){
      *(short8*)&lah[sr*40 + sc] = *(const short8*)&Ah[(m0+sr)*384 + k0 + sc];
      *(short8*)&lal[sr*40 + sc] = *(const short8*)&Al[(m0+sr)*384 + k0 + sc];
    }
    *(short8*)&lbh[sr*40 + sc] = *(const short8*)&Bh[(n0+sr)*384 + k0 + sc];
    *(short8*)&lbl[sr*40 + sc] = *(const short8*)&Bl[(n0+sr)*384 + k0 + sc];
    __syncthreads();
    short8 a_h = *(short8*)&lah[(ms+fr)*40 + (fg<<3)];
    short8 a_l = *(short8*)&lal[(ms+fr)*40 + (fg<<3)];
    #pragma unroll
    for (int cf=0; cf<2; cf++){
      short8 b_h = *(short8*)&lbh[(ns + cf*16 + fr)*40 + (fg<<3)];
      short8 b_l = *(short8*)&lbl[(ns + cf*16 + fr)*40 + (fg<<3)];
      acc[cf] = MFMA16(a_h, b_h, acc[cf]);
      acc[cf] = MFMA16(a_h, b_l, acc[cf]);
      acc[cf] = MFMA16(a_l, b_h, acc[cf]);
    }
    __syncthreads();
  }
  #pragma unroll
  for (int cf=0; cf<2; cf++){
    #pragma unroll
    for (int jj=0; jj<4; jj++){
      int row = m0 + ms + (fg<<2) + jj;
      int col = n0 + ns + cf*16 + fr;
      out[row*384 + col] = (acc[cf][jj] + bo[col]) * g[row*384 + col];
    }
  }
}

// ---------------- launch ----------------
extern "C" void kernel_launch(void* const* d_in, const int* in_sizes, int n_in,
                              void* d_out, int out_size, void* d_ws, size_t ws_size,
                              hipStream_t stream) {
  const float* s   = (const float*)d_in[0];
  const float* z   = (const float*)d_in[1];
  const int*   zm  = (const int*)d_in[2];
  const float* w_s = (const float*)d_in[3];
  const float* w_z = (const float*)d_in[4];
  const float* Wz  = (const float*)d_in[5];
  const float* Wq  = (const float*)d_in[6];
  const float* Wk  = (const float*)d_in[7];
  const float* Wv  = (const float*)d_in[8];
  const float* Wg  = (const float*)d_in[9];
  const float* bg  = (const float*)d_in[10];
  const float* Wo  = (const float*)d_in[11];
  const float* bo  = (const float*)d_in[12];
  float* out = (float*)d_out;
  char* ws = (char*)d_ws;

  unsigned short* s_hi  = (unsigned short*)(ws + 0);
  unsigned short* s_lo  = (unsigned short*)(ws + 786432);
  unsigned short* wt_hi = (unsigned short*)(ws + 1572864);   // [1920][384]
  unsigned short* wt_lo = (unsigned short*)(ws + 3047424);
  unsigned short* wwh   = (unsigned short*)(ws + 4521984);   // [128][16] bf16 hi
  unsigned short* wwl2  = (unsigned short*)(ws + 4526080);   // [128][16] bf16 lo
  unsigned short* q_hi  = (unsigned short*)(ws + 4532224);   // [12][1024][32]
  unsigned short* q_lo  = (unsigned short*)(ws + 5318656);
  unsigned short* k_hi  = (unsigned short*)(ws + 6105088);
  unsigned short* k_lo  = (unsigned short*)(ws + 6891520);
  unsigned short* v_hi  = (unsigned short*)(ws + 7677952);   // [12][32][1024] (transposed)
  unsigned short* v_lo  = (unsigned short*)(ws + 8464384);
  float*          gbuf  = (float*)(ws + 9250816);            // [1024][384] fp32
  unsigned short* o_hi  = (unsigned short*)(ws + 10823680);  // [1024][384]
  unsigned short* o_lo  = (unsigned short*)(ws + 11610112);
  __half*         biasH = (__half*)(ws + 12396544);          // [1024][12][1024] fp16, 24MB

  prep_all<<<977, 256, 0, stream>>>(Wq, Wk, Wv, Wg, Wo, w_z, Wz, s, w_s,
                                    wt_hi, wt_lo, wwh, wwl2, s_hi, s_lo);
  qkvg_bias_k<<<2432, 256, 0, stream>>>(s_hi, s_lo, wt_hi, wt_lo, bg,
                                        q_hi, q_lo, k_hi, k_lo, v_hi, v_lo, gbuf,
                                        z, zm, wwh, wwl2, biasH);
  attn_k<<<384, 256, 0, stream>>>(q_hi, q_lo, k_hi, k_lo, v_hi, v_lo, biasH, o_hi, o_lo);
  gemm_out_k<<<dim3(6,32), 256, 0, stream>>>(o_hi, o_lo,
                                             wt_hi + 1536*384, wt_lo + 1536*384,
                                             bo, gbuf, out);
}